// Round 2
// baseline (1063.174 us; speedup 1.0000x reference)
//
#include <hip/hip_runtime.h>
#include <math.h>

// GAT node weigher, restructured:
//   score[n] = leakyrelu( wx[n]·v + fx[n]·wa2 ),  v = W_fc^T @ wa1  (128-vec)
//   out[n]   = exp(score - segmax[g]) / segsum[g] * (N/G)
// Memory-bound: ~1.06 GB mandatory traffic -> ~170 us roofline.
// d_out doubles as the score/e buffer (N f32, fully overwritten each launch),
// so d_ws only holds segmax/segsum (~66 KB).

#define GCAP 8192  // max supported num_graphs for ws layout (actual G=512)

__device__ __forceinline__ unsigned fkey(float f) {
  unsigned u = __float_as_uint(f);
  return (u & 0x80000000u) ? ~u : (u | 0x80000000u);  // order-preserving; key(-inf) > 0
}
__device__ __forceinline__ float funkey(unsigned k) {
  unsigned u = (k & 0x80000000u) ? (k & 0x7fffffffu) : ~k;
  return __uint_as_float(u);
}

// K1: one block. v[d] = sum_j W_fc[j][d] * W_attn[j]; init segmax/segsum.
__global__ void init_kernel(const float* __restrict__ W_fc, const float* __restrict__ W_attn,
                            const int* __restrict__ num_graphs,
                            float* __restrict__ v, unsigned* __restrict__ segmax,
                            float* __restrict__ segsum) {
  const int t = threadIdx.x;
  const int G = *num_graphs;
  for (int i = t; i < G; i += blockDim.x) { segmax[i] = 0u; segsum[i] = 0.0f; }
  if (t < 128) {
    float acc = 0.0f;
    for (int j = 0; j < 256; ++j) acc += W_fc[j * 128 + t] * W_attn[j];
    v[t] = acc;
  }
}

// K2: one wave per contiguous chunk of nodes; lane l handles elems [2l,2l+1].
// Butterfly reduce -> score; running per-segment max (sorted ids -> ~2 atomics/wave).
__global__ void score_kernel(const float* __restrict__ wx, const float* __restrict__ fx,
                             const int* __restrict__ seg, const float* __restrict__ v,
                             const float* __restrict__ W_attn,
                             float* __restrict__ score, unsigned* __restrict__ segmax,
                             int N) {
  const int lane = threadIdx.x & 63;
  const int wid  = (blockIdx.x * blockDim.x + threadIdx.x) >> 6;
  const int nW   = (gridDim.x * blockDim.x) >> 6;
  const int chunk = (N + nW - 1) / nW;
  const int n0 = wid * chunk;
  const int n1 = min(n0 + chunk, N);
  if (n0 >= N) return;

  const float2 vv = ((const float2*)v)[lane];                // v[2l],v[2l+1]
  const float2 ww = ((const float2*)(W_attn + 256))[lane];   // wa2[2l],wa2[2l+1]

  int   curSeg = -1;
  float curMax = 0.0f;
  for (int n = n0; n < n1; ++n) {
    const float2 x = ((const float2*)(wx + (size_t)n * 128))[lane];
    const float2 f = ((const float2*)(fx + (size_t)n * 128))[lane];
    float p = x.x * vv.x + x.y * vv.y + f.x * ww.x + f.y * ww.y;
#pragma unroll
    for (int off = 32; off; off >>= 1) p += __shfl_xor(p, off);
    const float s = (p >= 0.0f) ? p : 0.1f * p;  // LeakyReLU(0.1)
    if (lane == 0) score[n] = s;
    const int sg = seg[n];  // wave-uniform broadcast load
    if (sg != curSeg) {
      if (curSeg >= 0 && lane == 0) atomicMax(&segmax[curSeg], fkey(curMax));
      curSeg = sg;
      curMax = s;
    } else {
      curMax = fmaxf(curMax, s);
    }
  }
  if (curSeg >= 0 && lane == 0) atomicMax(&segmax[curSeg], fkey(curMax));
}

// K3: e[n] = exp(score - segmax), in-place over score; wave-aggregated segment
// sums (ids sorted -> ~97% of waves are segment-uniform).
__global__ void exp_kernel(const float* __restrict__ score, const int* __restrict__ seg,
                           const unsigned* __restrict__ segmax,
                           float* __restrict__ e, float* __restrict__ segsum, int N) {
  const int n    = blockIdx.x * blockDim.x + threadIdx.x;
  const int lane = threadIdx.x & 63;
  const int nc   = min(n, N - 1);
  const int sg   = seg[nc];
  const float s  = score[nc];
  const float m  = funkey(segmax[sg]);
  const float ev = (n < N) ? expf(s - m) : 0.0f;  // pad lanes contribute 0
  if (n < N) e[n] = ev;

  const int sg0 = __shfl(sg, 0);
  if (__all(sg == sg0)) {
    float sum = ev;
#pragma unroll
    for (int off = 32; off; off >>= 1) sum += __shfl_xor(sum, off);
    if (lane == 0) atomicAdd(&segsum[sg0], sum);
  } else if (n < N) {
    atomicAdd(&segsum[sg], ev);  // rare: segment-boundary waves only
  }
}

// K4: out = (e / segsum) * (N/G), in-place over e.
__global__ void out_kernel(const float* __restrict__ e, const int* __restrict__ seg,
                           const float* __restrict__ segsum,
                           const int* __restrict__ num_graphs,
                           float* __restrict__ out, int N) {
  const int n = blockIdx.x * blockDim.x + threadIdx.x;
  if (n >= N) return;
  const float scale = (float)N / (float)(*num_graphs);  // == mean node count, exact
  out[n] = (e[n] / segsum[seg[n]]) * scale;
}

extern "C" void kernel_launch(void* const* d_in, const int* in_sizes, int n_in,
                              void* d_out, int out_size, void* d_ws, size_t ws_size,
                              hipStream_t stream) {
  const float* wx     = (const float*)d_in[0];  // [N,128]
  const float* fx     = (const float*)d_in[1];  // [N,128]
  const float* W_fc   = (const float*)d_in[2];  // [256,128]
  const float* W_attn = (const float*)d_in[3];  // [1,384]
  const int*   seg    = (const int*)d_in[4];    // [N], sorted
  const int*   nGptr  = (const int*)d_in[5];    // scalar
  float*       out    = (float*)d_out;          // [N] — also used as score/e buffer
  const int N = in_sizes[0] / 128;

  char* ws = (char*)d_ws;
  float*    v      = (float*)ws;                     // 128 f32
  unsigned* segmax = (unsigned*)(ws + 1024);         // GCAP u32
  float*    segsum = (float*)(ws + 1024 + 4 * GCAP); // GCAP f32

  init_kernel<<<1, 256, 0, stream>>>(W_fc, W_attn, nGptr, v, segmax, segsum);

  // 2048 blocks x 256 thr = 8192 waves = 256 CU x 32 waves -> full occupancy
  score_kernel<<<2048, 256, 0, stream>>>(wx, fx, seg, v, W_attn, out, segmax, N);

  const int nb = (N + 255) / 256;
  exp_kernel<<<nb, 256, 0, stream>>>(out, seg, segmax, out, segsum, N);
  out_kernel<<<nb, 256, 0, stream>>>(out, seg, segsum, nGptr, out, N);
}

// Round 4
// 1020.786 us; speedup vs baseline: 1.0415x; 1.0415x over previous
//
#include <hip/hip_runtime.h>
#include <math.h>

// GAT node weigher, restructured:
//   score[n] = leakyrelu( wx[n]·v + fx[n]·wa2 ),  v = W_fc^T @ wa1  (128-vec)
//   out[n]   = exp(score - segmax[g]) / segsum[g] * (N/G)
// Memory-bound: mandatory traffic = wx+fx reads (1.024 GB) + ~30 MB small
// passes -> ~170 us roofline at 6.3 TB/s. d_out doubles as score/e buffer.
//
// score_kernel: 2 nodes/iter (64 lanes x float4 = 1 KB contiguous per load),
// 5-step half-wave reduce, nontemporal loads, zero segment logic in hot loop.
// Segmax is a separate 4 MB pass with wave-aggregated atomics.

#define GCAP 8192  // max num_graphs supported by ws layout (actual G=512)

typedef float f4 __attribute__((ext_vector_type(4)));

__device__ __forceinline__ unsigned fkey(float f) {
  unsigned u = __float_as_uint(f);
  return (u & 0x80000000u) ? ~u : (u | 0x80000000u);  // order-preserving; key(-inf) > 0
}
__device__ __forceinline__ float funkey(unsigned k) {
  unsigned u = (k & 0x80000000u) ? (k & 0x7fffffffu) : ~k;
  return __uint_as_float(u);
}

// K1: one block. v[d] = sum_j W_fc[j][d]*W_attn[j]; zero segmax/segsum.
__global__ void init_kernel(const float* __restrict__ W_fc, const float* __restrict__ W_attn,
                            const int* __restrict__ num_graphs,
                            float* __restrict__ v, unsigned* __restrict__ segmax,
                            float* __restrict__ segsum) {
  const int t = threadIdx.x;
  const int G = *num_graphs;
  for (int i = t; i < G; i += blockDim.x) { segmax[i] = 0u; segsum[i] = 0.0f; }
  if (t < 128) {
    float acc = 0.0f;
    for (int j = 0; j < 256; ++j) acc += W_fc[j * 128 + t] * W_attn[j];
    v[t] = acc;
  }
}

// K2: streaming scores. One wave handles 2 nodes/iter: lanes 0-31 -> node 2p,
// lanes 32-63 -> node 2p+1; lane q covers elems [4q,4q+3]. Pure loads+FMA+
// 5-step butterfly; no atomics, no seg[], no loop-carried deps.
__global__ void score_kernel(const float* __restrict__ wx, const float* __restrict__ fx,
                             const float* __restrict__ v, const float* __restrict__ W_attn,
                             float* __restrict__ score, int N) {
  const int lane = threadIdx.x & 63;
  const int q    = lane & 31;
  const int half = lane >> 5;
  const int wid  = (blockIdx.x * blockDim.x + threadIdx.x) >> 6;
  const int nW   = (gridDim.x * blockDim.x) >> 6;
  const int pairs = (N + 1) >> 1;
  const int chunk = (pairs + nW - 1) / nW;
  const int p0 = wid * chunk;
  const int p1 = min(p0 + chunk, pairs);

  const f4 vv = ((const f4*)v)[q];              // v[4q..4q+3]
  const f4 ww = ((const f4*)(W_attn + 256))[q]; // wa2[4q..4q+3]

#pragma unroll 2
  for (int p = p0; p < p1; ++p) {
    const size_t base = (size_t)p * 256;        // 2 nodes = 256 floats = 1 KB
    const f4 x = __builtin_nontemporal_load(&((const f4*)(wx + base))[lane]);
    const f4 f = __builtin_nontemporal_load(&((const f4*)(fx + base))[lane]);
    float s = x.x * vv.x + x.y * vv.y + x.z * vv.z + x.w * vv.w
            + f.x * ww.x + f.y * ww.y + f.z * ww.z + f.w * ww.w;
#pragma unroll
    for (int off = 1; off < 32; off <<= 1) s += __shfl_xor(s, off);  // half-wave sum
    s = (s >= 0.0f) ? s : 0.1f * s;  // LeakyReLU(0.1)
    const int n = 2 * p + half;
    if (q == 0 && n < N) score[n] = s;
  }
}

// K3: per-segment max over score[] (4 MB pass), wave-aggregated (ids sorted).
__global__ void segmax_kernel(const float* __restrict__ score, const int* __restrict__ seg,
                              unsigned* __restrict__ segmax, int N) {
  const int n    = blockIdx.x * blockDim.x + threadIdx.x;
  const int lane = threadIdx.x & 63;
  const int nc   = min(n, N - 1);
  const int sg   = seg[nc];
  unsigned k = (n < N) ? fkey(score[nc]) : 0u;  // 0 == key(-inf): identity
  const int sg0 = __shfl(sg, 0);
  if (__all(sg == sg0)) {
#pragma unroll
    for (int off = 32; off; off >>= 1) {
      unsigned o = (unsigned)__shfl_xor((int)k, off);
      k = k > o ? k : o;
    }
    if (lane == 0) atomicMax(&segmax[sg0], k);
  } else if (n < N) {
    atomicMax(&segmax[sg], k);  // rare: segment-boundary waves only
  }
}

// K4: e[n] = exp(score - segmax), in-place; wave-aggregated segment sums.
__global__ void exp_kernel(const float* __restrict__ score, const int* __restrict__ seg,
                           const unsigned* __restrict__ segmax,
                           float* __restrict__ e, float* __restrict__ segsum, int N) {
  const int n    = blockIdx.x * blockDim.x + threadIdx.x;
  const int lane = threadIdx.x & 63;
  const int nc   = min(n, N - 1);
  const int sg   = seg[nc];
  const float s  = score[nc];
  const float m  = funkey(segmax[sg]);
  const float ev = (n < N) ? expf(s - m) : 0.0f;  // pad lanes contribute 0
  if (n < N) e[n] = ev;

  const int sg0 = __shfl(sg, 0);
  if (__all(sg == sg0)) {
    float sum = ev;
#pragma unroll
    for (int off = 32; off; off >>= 1) sum += __shfl_xor(sum, off);
    if (lane == 0) atomicAdd(&segsum[sg0], sum);
  } else if (n < N) {
    atomicAdd(&segsum[sg], ev);
  }
}

// K5: out = (e / segsum) * (N/G), in-place.
__global__ void out_kernel(const float* __restrict__ e, const int* __restrict__ seg,
                           const float* __restrict__ segsum,
                           const int* __restrict__ num_graphs,
                           float* __restrict__ out, int N) {
  const int n = blockIdx.x * blockDim.x + threadIdx.x;
  if (n >= N) return;
  const float scale = (float)N / (float)(*num_graphs);  // == mean node count, exact
  out[n] = (e[n] / segsum[seg[n]]) * scale;
}

extern "C" void kernel_launch(void* const* d_in, const int* in_sizes, int n_in,
                              void* d_out, int out_size, void* d_ws, size_t ws_size,
                              hipStream_t stream) {
  const float* wx     = (const float*)d_in[0];  // [N,128]
  const float* fx     = (const float*)d_in[1];  // [N,128]
  const float* W_fc   = (const float*)d_in[2];  // [256,128]
  const float* W_attn = (const float*)d_in[3];  // [1,384]
  const int*   seg    = (const int*)d_in[4];    // [N], sorted
  const int*   nGptr  = (const int*)d_in[5];    // scalar
  float*       out    = (float*)d_out;          // [N] — doubles as score/e buffer
  const int N = in_sizes[0] / 128;

  char* ws = (char*)d_ws;
  float*    v      = (float*)ws;                     // 128 f32
  unsigned* segmax = (unsigned*)(ws + 1024);         // GCAP u32
  float*    segsum = (float*)(ws + 1024 + 4 * GCAP); // GCAP f32

  init_kernel<<<1, 256, 0, stream>>>(W_fc, W_attn, nGptr, v, segmax, segsum);

  // 2048 blocks x 256 thr = 8192 waves = 256 CU x 32 -> full occupancy
  score_kernel<<<2048, 256, 0, stream>>>(wx, fx, v, W_attn, out, N);

  const int nb = (N + 255) / 256;
  segmax_kernel<<<nb, 256, 0, stream>>>(out, seg, segmax, N);
  exp_kernel<<<nb, 256, 0, stream>>>(out, seg, segmax, out, segsum, N);
  out_kernel<<<nb, 256, 0, stream>>>(out, seg, segsum, nGptr, out, N);
}